// Round 16
// baseline (375.534 us; speedup 1.0000x reference)
//
#include <hip/hip_runtime.h>
#include <math.h>

#define NN 4096
#define EE 65536
#define E2 (2*EE)
#define DEG 8
#define NPROTO 64
#define REP 128
#define TOPKK 5
#define SINKI 20
#define SB 256          // sink partial slots per (mat,k)

typedef __attribute__((ext_vector_type(8))) short short8;
typedef __attribute__((ext_vector_type(4))) float f32x4;
typedef __attribute__((ext_vector_type(8))) __bf16 bf16x8;
typedef __attribute__((ext_vector_type(4))) unsigned short us4;
typedef unsigned short u16;
typedef unsigned int u32;

__device__ __forceinline__ float b2f(u32 u){
  union { float f; u32 i; } v; v.i = u<<16; return v.f;
}
__device__ __forceinline__ u16 f2b(float f){
  __bf16 h = (__bf16)f;
  return __builtin_bit_cast(u16, h);
}
__device__ __forceinline__ u32 pk2(float lo, float hi){
  return (u32)f2b(lo) | ((u32)f2b(hi)<<16);
}
__device__ __forceinline__ us4 pk4(float a, float b, float c, float d){
  us4 o; o.x=f2b(a); o.y=f2b(b); o.z=f2b(c); o.w=f2b(d); return o;
}
__device__ __forceinline__ f32x4 MFMA_BF16(short8 a, short8 b, f32x4 c){
  return __builtin_amdgcn_mfma_f32_16x16x32_bf16(
      __builtin_bit_cast(bf16x8, a), __builtin_bit_cast(bf16x8, b), c, 0, 0, 0);
}
__device__ __forceinline__ void stage16(const u16* g, u16* l){
  typedef __attribute__((address_space(1))) const unsigned int gu32;
  typedef __attribute__((address_space(3))) unsigned int lu32;
  __builtin_amdgcn_global_load_lds((gu32*)g, (lu32*)l, 16, 0, 0);
}
__device__ __forceinline__ float wsum(float v){
  #pragma unroll
  for(int m=32;m>=1;m>>=1) v += __shfl_xor(v,m);
  return v;
}
__device__ __forceinline__ float r16sum(float v){
  #pragma unroll
  for(int m=8;m>=1;m>>=1) v += __shfl_xor(v,m);
  return v;
}
__device__ __forceinline__ float softplusf(float x){
  if(x > 20.f) return x;
  if(x < -20.f) return __expf(x);
  return log1pf(__expf(x));
}

// ---------------- fused prep: topk + weight packing + input bf16 conversion ----------------
__global__ __launch_bounds__(256) void k_prep(
    const int* __restrict__ ei, const float* __restrict__ ew, int* __restrict__ topk,
    const float* __restrict__ Wp1, const float* __restrict__ Wl1, const float* __restrict__ Wr1,
    const float* __restrict__ Wp2, const float* __restrict__ Wl2, const float* __restrict__ Wr2,
    const float* __restrict__ Wenc, const float* __restrict__ Wproto, const float* __restrict__ Wnc,
    u16* __restrict__ Wp1b, u16* __restrict__ Wc1b, u16* __restrict__ Wp2b, u16* __restrict__ Wc2b,
    u16* __restrict__ Wencb, u16* __restrict__ Wprotob, u16* __restrict__ Wncb,
    const float* __restrict__ x, const float* __restrict__ y, u16* __restrict__ XY){
  const int NW = 4096+16384+16384+32768+16384+8192+16384; // 110592 weight elems
  const int N4 = EE*64/4;
  const int TOTAL = 4096 + NW + 2*N4;
  for(int t0 = blockIdx.x*256+threadIdx.x; t0 < TOTAL; t0 += gridDim.x*256){
    int t = t0;
    if(t < 4096){
      int i = t;
      float val[DEG+1]; int idx[DEG+1]; bool used[DEG+1];
      val[0] = 1.0f; idx[0] = i; used[0]=false;
      for(int k=0;k<DEG;k++){
        int e = i*DEG + k;
        val[k+1] = ew[e];
        idx[k+1] = ei[NN*DEG + e];
        used[k+1] = false;
      }
      for(int s=0;s<TOPKK;s++){
        int best = -1;
        for(int k=0;k<=DEG;k++){
          if(used[k]) continue;
          if(best<0 || val[k]>val[best] || (val[k]==val[best] && idx[k]<idx[best])) best=k;
        }
        used[best]=true;
        topk[i*TOPKK+s]=idx[best];
      }
      continue;
    }
    t -= 4096;
    if(t < NW){
      if(t < 4096){ Wp1b[t]=f2b(Wp1[t]); continue; } t-=4096;
      if(t < 16384){ int c=t>>7, k=t&127;
        Wc1b[t]=f2b(k<64? Wl1[c*64+k] : Wr1[c*64+k-64]); continue; } t-=16384;
      if(t < 16384){ Wp2b[t]=f2b(Wp2[t]); continue; } t-=16384;
      if(t < 32768){ int c=t>>8, k=t&255;
        Wc2b[t]=f2b(k<128? Wl2[c*128+k] : Wr2[c*128+k-128]); continue; } t-=32768;
      if(t < 16384){ Wencb[t]=f2b(Wenc[t]); continue; } t-=16384;
      if(t < 8192){ Wprotob[t]=f2b(Wproto[t]); continue; } t-=8192;
      Wncb[t]=f2b(Wnc[t]); continue;
    }
    t -= NW;
    const float* s = (t<N4)? y : x;
    int k = (t<N4)? t : t-N4;
    float4 v = ((const float4*)s)[k];
    ((us4*)XY)[t] = pk4(v.x, v.y, v.z, v.w);
  }
}

// ---------------- single fused encoder: XY -> Z, INVN, M ----------------
// Local rows Lr = global - (n0-16). Slots: 152 rows x 64 cols bf16 (19456 B).
// s0..s3 lifetimes: XY, hp1, mean1 | T1a/T1b (h1) | B2/C2 (hp2/mean2) | h2 | Znorm
__global__ __launch_bounds__(256)
void k_enc(const u16* __restrict__ XY,
           const u16* __restrict__ Wp1b, const float* __restrict__ bp1,
           const u16* __restrict__ Wc1b, const float* __restrict__ bl1,
           const u16* __restrict__ Wp2b, const float* __restrict__ bp2,
           const u16* __restrict__ Wc2b, const float* __restrict__ bl2,
           const u16* __restrict__ Wencb, const float* __restrict__ benc,
           const u16* __restrict__ Wprotob,
           u16* __restrict__ Z, float* __restrict__ INVN, u16* __restrict__ Mout){
  __shared__ __align__(16) char arena[77824];   // 4 slots x 19456
  __shared__ float lnorm[2][128];
  char* s0c = arena;
  char* s1c = arena + 19456;
  char* s2c = arena + 38912;
  char* s3c = arena + 58368;
  const int tid = threadIdx.x;
  const int w = tid>>6, l = tid&63;
  const int lr = l&15, kg = l>>4;
  const long rb0 = (long)blockIdx.x*128;
  const long n0 = rb0 & (NN-1), sbase = rb0 - n0;
  const int sw = (lr&7)<<4;

  // P1: stage XY halo rows [n0-16, n0+128) -> s0 (144 rows, swizzled source)
  for(int c=w;c<18;c+=4){
    int off=c*1024+l*16, row=off>>7;
    int cu=(off&127)^((row&7)<<4);
    long gn=(n0-16+row)&(NN-1);
    stage16(XY+(sbase+gn)*64+(cu>>1), (u16*)s0c+c*512);
  }
  __syncthreads();

  // P2: hp1 = relu(XY@Wp1^T+bp1), rows 0..143 -> s1
  for(int g=w; g<9; g+=4){
    const int row = g*16 + lr;
    const char* base = s0c + row*128;
    short8 af0 = *(const short8*)(base + ((kg*16)^sw));
    short8 af1 = *(const short8*)(base + ((64+kg*16)^sw));
    f32x4 a4[4];
    #pragma unroll
    for(int cf=0;cf<4;cf++){
      a4[cf]=(f32x4){0.f,0.f,0.f,0.f};
      int ch=cf*16+lr;
      short8 wf0 = *(const short8*)(Wp1b + ch*64 + kg*8);
      short8 wf1 = *(const short8*)(Wp1b + ch*64 + 32 + kg*8);
      a4[cf]=MFMA_BF16(wf0, af0, a4[cf]);
      a4[cf]=MFMA_BF16(wf1, af1, a4[cf]);
    }
    #pragma unroll
    for(int cf=0;cf<4;cf++){
      int c0=cf*16+kg*4;
      float4 bv=*(const float4*)(bp1+c0);
      us4 o = pk4(fmaxf(a4[cf][0]+bv.x,0.f), fmaxf(a4[cf][1]+bv.y,0.f),
                  fmaxf(a4[cf][2]+bv.z,0.f), fmaxf(a4[cf][3]+bv.w,0.f));
      *(us4*)(s1c + row*128 + ((c0*2)^((row&7)<<4))) = o;
    }
  }
  __syncthreads();

  // P3: mean1 rows 8..143 (s1 -> s2), 8 stripes x 17
  {
    const int s=tid>>5, cp=tid&31;
    const u32* B = (const u32*)s1c;
    u32* C = (u32*)s2c;
    const int row0 = 8 + s*17;
    float a0=0.f,a1=0.f;
    #pragma unroll
    for(int t=0;t<8;t++){
      int r=row0-8+t;
      u32 v=B[r*32+(cp^((r&7)<<2))];
      a0+=b2f(v&0xffffu); a1+=b2f(v>>16);
    }
    #pragma unroll
    for(int i=0;i<17;i++){
      int r=row0+i;
      C[r*32+(cp^((r&7)<<2))] = pk2(a0*0.125f, a1*0.125f);
      if(i<16){
        u32 va=B[r*32+(cp^((r&7)<<2))];
        u32 vs=B[(r-8)*32+(cp^((r&7)<<2))];
        a0+=b2f(va&0xffffu)-b2f(vs&0xffffu);
        a1+=b2f(va>>16)-b2f(vs>>16);
      }
    }
  }
  __syncthreads();

  // P4: h1 = relu([mean1|XY]@Wc1^T+bl1), rows 8..143 (guard) -> T1a(s1), T1b(s3)
  for(int g=w; g<9; g+=4){
    const int row = 8 + g*16 + lr;
    short8 afm[2], afx[2];
    { const char* bm = s2c + row*128;
      afm[0] = *(const short8*)(bm + ((kg*16)^sw));
      afm[1] = *(const short8*)(bm + ((64+kg*16)^sw));
      const char* bx = s0c + row*128;
      afx[0] = *(const short8*)(bx + ((kg*16)^sw));
      afx[1] = *(const short8*)(bx + ((64+kg*16)^sw)); }
    f32x4 a8[8];
    #pragma unroll
    for(int cf=0;cf<8;cf++){
      a8[cf]=(f32x4){0.f,0.f,0.f,0.f};
      int ch=cf*16+lr;
      short8 w0 = *(const short8*)(Wc1b + (long)ch*128 + kg*8);
      short8 w1 = *(const short8*)(Wc1b + (long)ch*128 + 32 + kg*8);
      short8 w2 = *(const short8*)(Wc1b + (long)ch*128 + 64 + kg*8);
      short8 w3 = *(const short8*)(Wc1b + (long)ch*128 + 96 + kg*8);
      a8[cf]=MFMA_BF16(w0, afm[0], a8[cf]);
      a8[cf]=MFMA_BF16(w1, afm[1], a8[cf]);
      a8[cf]=MFMA_BF16(w2, afx[0], a8[cf]);
      a8[cf]=MFMA_BF16(w3, afx[1], a8[cf]);
    }
    if(row < 144){
      #pragma unroll
      for(int cf=0;cf<8;cf++){
        int c0=cf*16+kg*4;
        float4 bv=*(const float4*)(bl1+c0);
        us4 o = pk4(fmaxf(a8[cf][0]+bv.x,0.f), fmaxf(a8[cf][1]+bv.y,0.f),
                    fmaxf(a8[cf][2]+bv.z,0.f), fmaxf(a8[cf][3]+bv.w,0.f));
        int cl = (cf&3)*16 + kg*4;
        char* dst = (cf<4)? s1c : s3c;
        *(us4*)(dst + row*128 + ((cl*2)^((row&7)<<4))) = o;
      }
    }
  }
  __syncthreads();

  // P5: hp2 = relu(h1@Wp2^T+bp2), rows 8..143 (guard) -> B2a(s0), B2b(s2)
  for(int g=w; g<9; g+=4){
    const int row = 8 + g*16 + lr;
    short8 afa[2], afb[2];
    { const char* ba = s1c + row*128;
      afa[0] = *(const short8*)(ba + ((kg*16)^sw));
      afa[1] = *(const short8*)(ba + ((64+kg*16)^sw));
      const char* bb = s3c + row*128;
      afb[0] = *(const short8*)(bb + ((kg*16)^sw));
      afb[1] = *(const short8*)(bb + ((64+kg*16)^sw)); }
    f32x4 a8[8];
    #pragma unroll
    for(int cf=0;cf<8;cf++){
      a8[cf]=(f32x4){0.f,0.f,0.f,0.f};
      int ch=cf*16+lr;
      short8 w0 = *(const short8*)(Wp2b + (long)ch*128 + kg*8);
      short8 w1 = *(const short8*)(Wp2b + (long)ch*128 + 32 + kg*8);
      short8 w2 = *(const short8*)(Wp2b + (long)ch*128 + 64 + kg*8);
      short8 w3 = *(const short8*)(Wp2b + (long)ch*128 + 96 + kg*8);
      a8[cf]=MFMA_BF16(w0, afa[0], a8[cf]);
      a8[cf]=MFMA_BF16(w1, afa[1], a8[cf]);
      a8[cf]=MFMA_BF16(w2, afb[0], a8[cf]);
      a8[cf]=MFMA_BF16(w3, afb[1], a8[cf]);
    }
    if(row < 144){
      #pragma unroll
      for(int cf=0;cf<8;cf++){
        int c0=cf*16+kg*4;
        float4 bv=*(const float4*)(bp2+c0);
        us4 o = pk4(fmaxf(a8[cf][0]+bv.x,0.f), fmaxf(a8[cf][1]+bv.y,0.f),
                    fmaxf(a8[cf][2]+bv.z,0.f), fmaxf(a8[cf][3]+bv.w,0.f));
        int cl = (cf&3)*16 + kg*4;
        char* dst = (cf<4)? s0c : s2c;
        *(us4*)(dst + row*128 + ((cl*2)^((row&7)<<4))) = o;
      }
    }
  }
  __syncthreads();

  // P6: mean2 rows 16..143, in-place over s0/s2 (read->regs, sync, write)
  {
    const int s=tid>>5, cp=tid&31;
    const u32* B0 = (const u32*)s0c;
    const u32* B1 = (const u32*)s2c;
    const int row0 = 16 + s*16;
    float a0=0.f,a1=0.f,c0=0.f,c1=0.f;
    #pragma unroll
    for(int t=0;t<8;t++){
      int r=row0-8+t;
      u32 v0=B0[r*32+(cp^((r&7)<<2))]; a0+=b2f(v0&0xffffu); a1+=b2f(v0>>16);
      u32 v1=B1[r*32+(cp^((r&7)<<2))]; c0+=b2f(v1&0xffffu); c1+=b2f(v1>>16);
    }
    u32 oa[16], ob[16];
    #pragma unroll
    for(int i=0;i<16;i++){
      int r=row0+i;
      oa[i]=pk2(a0*0.125f, a1*0.125f);
      ob[i]=pk2(c0*0.125f, c1*0.125f);
      u32 va0=B0[r*32+(cp^((r&7)<<2))], vs0=B0[(r-8)*32+(cp^((r&7)<<2))];
      a0+=b2f(va0&0xffffu)-b2f(vs0&0xffffu);
      a1+=b2f(va0>>16)-b2f(vs0>>16);
      u32 va1=B1[r*32+(cp^((r&7)<<2))], vs1=B1[(r-8)*32+(cp^((r&7)<<2))];
      c0+=b2f(va1&0xffffu)-b2f(vs1&0xffffu);
      c1+=b2f(va1>>16)-b2f(vs1>>16);
    }
    __syncthreads();
    u32* W0=(u32*)s0c; u32* W1=(u32*)s2c;
    #pragma unroll
    for(int i=0;i<16;i++){
      int r=row0+i;
      int idx=r*32+(cp^((r&7)<<2));
      W0[idx]=oa[i];
      W1[idx]=ob[i];
    }
  }
  __syncthreads();

  // P7: dual2 = [mean2|h1] @ Wc2^T, 128 rows (local 16..143), 4-wave structure
  const int rw = w&1, cw = w>>1;
  const int rowoff = rw*64, cbase = cw*64;
  f32x4 acc[4][4];
  #pragma unroll
  for(int a=0;a<4;a++)
    #pragma unroll
    for(int b=0;b<4;b++) acc[a][b]=(f32x4){0.f,0.f,0.f,0.f};
  #pragma unroll
  for(int kc=0;kc<4;kc++){
    const char* Ab = (kc==0)? s0c : (kc==1)? s2c : (kc==2)? s1c : s3c;
    short8 af[4][2];
    #pragma unroll
    for(int f=0;f<4;f++){
      const char* base = Ab + (16+rowoff+f*16+lr)*128;
      af[f][0] = *(const short8*)(base + ((kg*16)^sw));
      af[f][1] = *(const short8*)(base + ((64+kg*16)^sw));
    }
    #pragma unroll
    for(int cf=0;cf<4;cf++){
      const int ch = cbase + cf*16 + lr;
      short8 wf0 = *(const short8*)(Wc2b + (long)ch*256 + kc*64 + kg*8);
      short8 wf1 = *(const short8*)(Wc2b + (long)ch*256 + kc*64 + 32 + kg*8);
      #pragma unroll
      for(int f=0;f<4;f++){
        acc[cf][f] = MFMA_BF16(wf0, af[f][0], acc[cf][f]);
        acc[cf][f] = MFMA_BF16(wf1, af[f][1], acc[cf][f]);
      }
    }
  }
  __syncthreads();   // all slot reads done

  // P8: h2 = relu(acc+bl2) -> s0 (cols 0-63), s1 (cols 64-127)
  #pragma unroll
  for(int f=0;f<4;f++){
    const int row = 16 + rowoff + f*16 + lr;
    #pragma unroll
    for(int cf=0;cf<4;cf++){
      const int c0 = cbase + cf*16 + kg*4;
      float4 bv = *(const float4*)(bl2 + c0);
      us4 o = pk4(fmaxf(acc[cf][f][0]+bv.x,0.f), fmaxf(acc[cf][f][1]+bv.y,0.f),
                  fmaxf(acc[cf][f][2]+bv.z,0.f), fmaxf(acc[cf][f][3]+bv.w,0.f));
      int cl = (c0 & 63)*2;
      char* dst = (c0<64)? s0c : s1c;
      *(us4*)(dst + row*128 + (cl^((row&7)<<4))) = o;
    }
  }
  __syncthreads();

  // P9: enc = h2@Wenc^T+benc; norms; Z global; Znorm -> s2/s3
  #pragma unroll
  for(int a=0;a<4;a++)
    #pragma unroll
    for(int b=0;b<4;b++) acc[a][b]=(f32x4){0.f,0.f,0.f,0.f};
  #pragma unroll
  for(int kc=0;kc<2;kc++){
    const char* Ab = kc? s1c : s0c;
    short8 af[4][2];
    #pragma unroll
    for(int f=0;f<4;f++){
      const char* base = Ab + (16+rowoff+f*16+lr)*128;
      af[f][0] = *(const short8*)(base + ((kg*16)^sw));
      af[f][1] = *(const short8*)(base + ((64+kg*16)^sw));
    }
    #pragma unroll
    for(int cf=0;cf<4;cf++){
      const int ch = cbase + cf*16 + lr;
      short8 wf0 = *(const short8*)(Wencb + (long)ch*128 + kc*64 + kg*8);
      short8 wf1 = *(const short8*)(Wencb + (long)ch*128 + kc*64 + 32 + kg*8);
      #pragma unroll
      for(int f=0;f<4;f++){
        acc[cf][f] = MFMA_BF16(wf0, af[f][0], acc[cf][f]);
        acc[cf][f] = MFMA_BF16(wf1, af[f][1], acc[cf][f]);
      }
    }
  }
  {
    float sn[4] = {0.f,0.f,0.f,0.f};
    #pragma unroll
    for(int f=0;f<4;f++){
      #pragma unroll
      for(int cf=0;cf<4;cf++){
        const int c0 = cbase + cf*16 + kg*4;
        float4 bv = *(const float4*)(benc + c0);
        float v0=acc[cf][f][0]+bv.x, v1=acc[cf][f][1]+bv.y;
        float v2=acc[cf][f][2]+bv.z, v3=acc[cf][f][3]+bv.w;
        sn[f] += v0*v0+v1*v1+v2*v2+v3*v3;
      }
      float s = sn[f];
      s += __shfl_xor(s, 16);
      s += __shfl_xor(s, 32);
      if(kg==0) lnorm[cw][rowoff + f*16 + lr] = s;
    }
  }
  __syncthreads();
  if(tid < 128){
    float s = lnorm[0][tid] + lnorm[1][tid];
    INVN[rb0 + tid] = 1.0f/fmaxf(sqrtf(s), 1e-12f);
  }
  #pragma unroll
  for(int f=0;f<4;f++){
    const int orow = rowoff + f*16 + lr;     // 0..127
    const int row = 16 + orow;
    float sr = lnorm[0][orow] + lnorm[1][orow];
    float inv = 1.0f/fmaxf(sqrtf(sr), 1e-12f);
    #pragma unroll
    for(int cf=0;cf<4;cf++){
      const int c0 = cbase + cf*16 + kg*4;
      float4 bv = *(const float4*)(benc + c0);
      float v0=acc[cf][f][0]+bv.x, v1=acc[cf][f][1]+bv.y;
      float v2=acc[cf][f][2]+bv.z, v3=acc[cf][f][3]+bv.w;
      *(us4*)(Z + (rb0+orow)*128 + c0) = pk4(v0,v1,v2,v3);
      int cl = (c0 & 63)*2;
      char* dst = (c0<64)? s2c : s3c;
      *(us4*)(dst + row*128 + (cl^((row&7)<<4))) = pk4(v0*inv,v1*inv,v2*inv,v3*inv);
    }
  }
  __syncthreads();

  // P10: proto: M = exp(20*(Znorm@Wproto^T))
  f32x4 acc3[2][4];
  #pragma unroll
  for(int a=0;a<2;a++)
    #pragma unroll
    for(int b=0;b<4;b++) acc3[a][b]=(f32x4){0.f,0.f,0.f,0.f};
  #pragma unroll
  for(int kc=0;kc<2;kc++){
    const char* Ab = kc? s3c : s2c;
    short8 af[4][2];
    #pragma unroll
    for(int f=0;f<4;f++){
      const char* base = Ab + (16+rowoff+f*16+lr)*128;
      af[f][0] = *(const short8*)(base + ((kg*16)^sw));
      af[f][1] = *(const short8*)(base + ((64+kg*16)^sw));
    }
    #pragma unroll
    for(int cf=0;cf<2;cf++){
      const int ch = cw*32 + cf*16 + lr;
      short8 wf0 = *(const short8*)(Wprotob + (long)ch*128 + kc*64 + kg*8);
      short8 wf1 = *(const short8*)(Wprotob + (long)ch*128 + kc*64 + 32 + kg*8);
      #pragma unroll
      for(int f=0;f<4;f++){
        acc3[cf][f] = MFMA_BF16(wf0, af[f][0], acc3[cf][f]);
        acc3[cf][f] = MFMA_BF16(wf1, af[f][1], acc3[cf][f]);
      }
    }
  }
  #pragma unroll
  for(int f=0;f<4;f++){
    const long row = rb0 + rowoff + f*16 + lr;
    #pragma unroll
    for(int cf=0;cf<2;cf++){
      const int c0 = cw*32 + cf*16 + kg*4;
      *(us4*)(Mout + row*64 + c0) = pk4(__expf(20.f*acc3[cf][f][0]), __expf(20.f*acc3[cf][f][1]),
                                        __expf(20.f*acc3[cf][f][2]), __expf(20.f*acc3[cf][f][3]));
    }
  }
}

// ---------------- sinkhorn iteration (bf16 M) ----------------
__global__ __launch_bounds__(256)
void k_sink2(const u16* __restrict__ M, const float* __restrict__ Pdprev,
             float* __restrict__ Pdcur, int it){
  __shared__ float T[4][64*33];
  __shared__ float ulds[NPROTO];
  __shared__ float redw[4][NPROTO];
  const int tid = threadIdx.x, b = blockIdx.x;
  const int wv = tid>>6, l = tid&63;
  const int mat = b>>8, bi = b&255;
  const long row = (long)mat*EE + (long)bi*256 + wv*64 + l;

  float m[64];
  #pragma unroll
  for(int j=0;j<8;j++){
    short8 v = *(const short8*)(M + row*64 + j*8);
    #pragma unroll
    for(int e=0;e<8;e++) m[j*8+e] = b2f((u16)v[e]);
  }

  if(it > 0 && tid < 128){
    int k = tid>>1, half = tid&1;
    const float4* src = (const float4*)(Pdprev + (long)(mat*64+k)*SB + half*128);
    float s = 0.f;
    #pragma unroll
    for(int j=0;j<32;j++){ float4 q = src[j]; s += q.x+q.y+q.z+q.w; }
    s += __shfl_xor(s, 1);
    if(half==0) ulds[k] = 1.0f/((float)NPROTO * s);
  }
  __syncthreads();

  float vv = 1.f;
  if(it > 0){
    float s = 0.f;
    #pragma unroll
    for(int k=0;k<64;k++) s += m[k]*ulds[k];
    vv = 1.0f/((float)EE * s);
  }

  float* Tw = &T[wv][0];
  const int col = l&31, rh = l>>5;
  #pragma unroll
  for(int h=0;h<2;h++){
    #pragma unroll
    for(int kk=0;kk<32;kk++) Tw[l*33+kk] = m[h*32+kk]*vv;
    __syncthreads();
    float s = 0.f;
    #pragma unroll
    for(int j=0;j<32;j++) s += Tw[(rh*32+j)*33 + col];
    s += __shfl_xor(s, 32);
    if(l<32) redw[wv][h*32+l] = s;
    __syncthreads();
  }
  if(tid < 64){
    float s = redw[0][tid]+redw[1][tid]+redw[2][tid]+redw[3][tid];
    Pdcur[(long)(mat*64+tid)*SB + bi] = s;
  }
}

// final d values (summed partials) for loss1
__global__ void k_ufinal(const float* __restrict__ Pdlast, float* __restrict__ D){
  int tid = threadIdx.x;              // 256
  int mk = tid>>1, half = tid&1;
  const float4* src = (const float4*)(Pdlast + (long)mk*SB + half*128);
  float s = 0.f;
  #pragma unroll
  for(int j=0;j<32;j++){ float4 q = src[j]; s += q.x+q.y+q.z+q.w; }
  s += __shfl_xor(s, 1);
  if(half==0) D[mk] = s;
}

// ---------------- prototype loss from M (16 lanes/row, 4 rows/wave) ----------------
__global__ __launch_bounds__(256) void k_loss1(const u16* __restrict__ M1, const u16* __restrict__ M2,
                                               const float* __restrict__ d1l, const float* __restrict__ d2l,
                                               float* __restrict__ p1){
  const int tid = threadIdx.x, wv = tid>>6;
  const int gw = blockIdx.x*4 + wv;
  const int l = tid&63, g = l>>4, li = l&15;
  const int nw = gridDim.x*4;
  float4 dv1 = ((const float4*)d1l)[li];
  float4 dv2 = ((const float4*)d2l)[li];
  const float inp = 1.0f/(float)NPROTO;
  float u1v[4] = { inp/dv1.x, inp/dv1.y, inp/dv1.z, inp/dv1.w };
  float u2v[4] = { inp/dv2.x, inp/dv2.y, inp/dv2.z, inp/dv2.w };
  const float i6 = 1.0f/6.0f;
  float lsum = 0.f;
  for(long r0 = (long)gw*4; r0 < EE; r0 += (long)nw*4){
    long r = r0 + g;
    uint2 w1 = ((const uint2*)(M1 + r*NPROTO))[li];
    uint2 w2 = ((const uint2*)(M2 + r*NPROTO))[li];
    float m1v[4] = { b2f(w1.x&0xffffu), b2f(w1.x>>16), b2f(w1.y&0xffffu), b2f(w1.y>>16) };
    float m2v[4] = { b2f(w2.x&0xffffu), b2f(w2.x>>16), b2f(w2.y&0xffffu), b2f(w2.y>>16) };
    float x1v[4], x2v[4], a1v[4], a2v[4];
    #pragma unroll
    for(int j=0;j<4;j++){
      x1v[j] = __logf(m1v[j])*i6;
      x2v[j] = __logf(m2v[j])*i6;
      a1v[j] = m1v[j]*u1v[j];
      a2v[j] = m2v[j]*u2v[j];
    }
    float S1 = r16sum(a1v[0]+a1v[1]+a1v[2]+a1v[3]);
    float S2 = r16sum(a2v[0]+a2v[1]+a2v[2]+a2v[3]);
    float mx1 = fmaxf(fmaxf(x1v[0],x1v[1]),fmaxf(x1v[2],x1v[3]));
    float mx2 = fmaxf(fmaxf(x2v[0],x2v[1]),fmaxf(x2v[2],x2v[3]));
    #pragma unroll
    for(int m=8;m>=1;m>>=1){ mx1=fmaxf(mx1,__shfl_xor(mx1,m)); mx2=fmaxf(mx2,__shfl_xor(mx2,m)); }
    float Z1 = r16sum(__expf(x1v[0]-mx1)+__expf(x1v[1]-mx1)+__expf(x1v[2]-mx1)+__expf(x1v[3]-mx1));
    float Z2 = r16sum(__expf(x2v[0]-mx2)+__expf(x2v[1]-mx2)+__expf(x2v[2]-mx2)+__expf(x2v[3]-mx2));
    float o1 = mx1 + __logf(Z1);
    float o2 = mx2 + __logf(Z2);
    float t1 = r16sum(a1v[0]*(x2v[0]-o2)+a1v[1]*(x2v[1]-o2)+a1v[2]*(x2v[2]-o2)+a1v[3]*(x2v[3]-o2)) / S1;
    float t2 = r16sum(a2v[0]*(x1v[0]-o1)+a2v[1]*(x1v[1]-o1)+a2v[2]*(x1v[2]-o1)+a2v[3]*(x1v[3]-o1)) / S2;
    if(li==0) lsum += t1+t2;
  }
  lsum = wsum(lsum);
  __shared__ float red[4];
  if(l==0) red[wv]=lsum;
  __syncthreads();
  if(tid==0) p1[blockIdx.x] = red[0]+red[1]+red[2]+red[3];
}

// ---------------- fused attention + Wnc GEMM ----------------
__global__ __launch_bounds__(256)
void k_attnc(const u16* __restrict__ Z1, const int* __restrict__ topk,
             const float* __restrict__ Wsa, const float* __restrict__ bsa,
             const u16* __restrict__ Wncb, const float* __restrict__ bnc,
             u16* __restrict__ ANS, float* __restrict__ ansn){
  __shared__ __align__(16) u16 T[128*128];
  __shared__ float lnorm[2][128];
  const int tid = threadIdx.x;
  const int w = tid>>6, l = tid&63;
  const int lr = l&15, kg = l>>4;
  const int g = l>>4, li = l&15;
  const long rb0 = (long)blockIdx.x*128;

  float2 wsa[4];
  #pragma unroll
  for(int j=0;j<4;j++) wsa[j] = ((const float2*)Wsa)[li*4+j];
  const float bs = bsa[0];
  for(int it=0; it<8; ++it){
    int row = it*16 + w*4 + g;     // 0..127
    long r = rb0 + row;
    int b = (int)(r >> 12);
    int n = (int)(r & (NN-1));
    u32 nb[TOPKK][4];
    float lg[TOPKK];
    #pragma unroll
    for(int k=0;k<TOPKK;k++){
      int idx = topk[n*TOPKK+k];
      uint4 v = ((const uint4*)(Z1 + ((long)(b<<12)+idx)*REP))[li];
      nb[k][0]=v.x; nb[k][1]=v.y; nb[k][2]=v.z; nb[k][3]=v.w;
      float s = 0.f;
      #pragma unroll
      for(int j=0;j<4;j++)
        s += b2f(nb[k][j]&0xffffu)*wsa[j].x + b2f(nb[k][j]>>16)*wsa[j].y;
      lg[k] = r16sum(s) + bs;
    }
    float mx = lg[0];
    #pragma unroll
    for(int k=1;k<TOPKK;k++) mx = fmaxf(mx,lg[k]);
    float Zs=0.f;
    #pragma unroll
    for(int k=0;k<TOPKK;k++){ lg[k]=__expf(lg[k]-mx); Zs+=lg[k]; }
    float iZ = 1.0f/Zs;
    uint4 o;
    u32 ov[4];
    #pragma unroll
    for(int j=0;j<4;j++){
      float o0=0.f, o1=0.f;
      #pragma unroll
      for(int k=0;k<TOPKK;k++){
        float a = lg[k]*iZ;
        o0 += a*b2f(nb[k][j]&0xffffu);
        o1 += a*b2f(nb[k][j]>>16);
      }
      ov[j] = pk2(o0, o1);
    }
    o.x=ov[0]; o.y=ov[1]; o.z=ov[2]; o.w=ov[3];
    *(uint4*)((char*)T + (long)row*256 + ((li*16)^((row&7)<<4))) = o;
  }
  __syncthreads();

  const int rw = w&1, cw = w>>1;
  const int rowoff = rw*64, cbase = cw*64;
  f32x4 acc[4][4];
  #pragma unroll
  for(int a=0;a<4;a++)
    #pragma unroll
    for(int b=0;b<4;b++) acc[a][b]=(f32x4){0.f,0.f,0.f,0.f};
  #pragma unroll
  for(int kc=0;kc<2;kc++){
    short8 af[4][2];
    #pragma unroll
    for(int f=0;f<4;f++){
      const char* base = (const char*)T + (rowoff+f*16+lr)*256;
      const int sw = (lr&7)<<4;
      af[f][0] = *(const short8*)(base + ((kc*128+kg*16)^sw));
      af[f][1] = *(const short8*)(base + ((kc*128+64+kg*16)^sw));
    }
    #pragma unroll
    for(int cf=0;cf<4;cf++){
      const int ch = cbase + cf*16 + lr;
      short8 wf0 = *(const short8*)(Wncb + (long)ch*128 + kc*64 + kg*8);
      short8 wf1 = *(const short8*)(Wncb + (long)ch*128 + kc*64 + 32 + kg*8);
      #pragma unroll
      for(int f=0;f<4;f++){
        acc[cf][f] = MFMA_BF16(wf0, af[f][0], acc[cf][f]);
        acc[cf][f] = MFMA_BF16(wf1, af[f][1], acc[cf][f]);
      }
    }
  }
  float sn[4] = {0.f,0.f,0.f,0.f};
  #pragma unroll
  for(int f=0;f<4;f++){
    const long row = rb0 + rowoff + f*16 + lr;
    #pragma unroll
    for(int cf=0;cf<4;cf++){
      const int c0 = cbase + cf*16 + kg*4;
      float4 bv = *(const float4*)(bnc + c0);
      float v0=acc[cf][f][0]+bv.x, v1=acc[cf][f][1]+bv.y;
      float v2=acc[cf][f][2]+bv.z, v3=acc[cf][f][3]+bv.w;
      sn[f] += v0*v0+v1*v1+v2*v2+v3*v3;
      *(us4*)(ANS + row*128 + c0) = pk4(v0,v1,v2,v3);
    }
  }
  #pragma unroll
  for(int f=0;f<4;f++){
    float s = sn[f];
    s += __shfl_xor(s, 16);
    s += __shfl_xor(s, 32);
    if(kg==0) lnorm[cw][rowoff + f*16 + lr] = s;
  }
  __syncthreads();
  if(tid < 128){
    float s = lnorm[0][tid] + lnorm[1][tid];
    ansn[rb0 + tid] = 1.0f/fmaxf(sqrtf(s), 1e-12f);
  }
}

// ---------------- discriminator loss + acc (16 lanes/row, 4 rows/wave) ----------------
__global__ __launch_bounds__(256) void k_loss2(const u16* __restrict__ Z2, const u16* __restrict__ ANS,
                                               const float* __restrict__ invn2, const float* __restrict__ ansn,
                                               const int* __restrict__ pb, const int* __restrict__ pn,
                                               float2* __restrict__ p2){
  const int tid = threadIdx.x, wv = tid>>6;
  const int gw = blockIdx.x*4 + wv;
  const int l = tid&63, g = l>>4, li = l&15;
  const int nw = gridDim.x*4;
  float lsum=0.f, asum=0.f;
  for(long r0 = (long)gw*4; r0 < EE; r0 += (long)nw*4){
    long r = r0 + g;
    int b = (int)(r>>12), n = (int)(r&(NN-1));
    long rfrow = (long)pb[b]*NN + pn[n];
    uint4 zv = ((const uint4*)(Z2 + r*REP))[li];
    uint4 av = ((const uint4*)(ANS + r*REP))[li];
    uint4 fv = ((const uint4*)(ANS + rfrow*REP))[li];
    float sr=0.f, sf=0.f;
    {
      u32 za[4]={zv.x,zv.y,zv.z,zv.w}, aa[4]={av.x,av.y,av.z,av.w}, fa[4]={fv.x,fv.y,fv.z,fv.w};
      #pragma unroll
      for(int j=0;j<4;j++){
        float z0=b2f(za[j]&0xffffu), z1=b2f(za[j]>>16);
        sr += z0*b2f(aa[j]&0xffffu) + z1*b2f(aa[j]>>16);
        sf += z0*b2f(fa[j]&0xffffu) + z1*b2f(fa[j]>>16);
      }
    }
    sr = r16sum(sr); sf = r16sum(sf);
    if(li==0){
      float in2 = invn2[r];
      float scrl = sr*in2*ansn[r];
      float scfk = sf*in2*ansn[rfrow];
      lsum += softplusf(-scrl) + softplusf(scfk);
      asum += (scrl>0.f?1.f:0.f) + (scfk>0.f?0.f:1.f);
    }
  }
  lsum = wsum(lsum); asum = wsum(asum);
  __shared__ float rl[4], ra[4];
  if(l==0){ rl[wv]=lsum; ra[wv]=asum; }
  __syncthreads();
  if(tid==0){
    float2 o; o.x=rl[0]+rl[1]+rl[2]+rl[3]; o.y=ra[0]+ra[1]+ra[2]+ra[3];
    p2[blockIdx.x]=o;
  }
}

__global__ void k_final(const float* __restrict__ p1, const float2* __restrict__ p2,
                        int n1, int n2, float* __restrict__ out){
  int l = threadIdx.x;        // 64 threads
  double s1=0,s2=0,sa=0;
  for(int i=l;i<n1;i+=64) s1 += (double)p1[i];
  for(int i=l;i<n2;i+=64){ float2 v=p2[i]; s2+=(double)v.x; sa+=(double)v.y; }
  #pragma unroll
  for(int m=32;m>=1;m>>=1){ s1+=__shfl_xor(s1,m); s2+=__shfl_xor(s2,m); sa+=__shfl_xor(sa,m); }
  if(l==0){
    double loss1 = -s1/(double)EE;
    double loss2 = s2/(double)(2*EE);
    double acc   = sa/(double)(2*EE);
    out[0]=(float)(loss1+loss2);
    out[1]=(float)acc;
  }
}

// ---------------- host ----------------
extern "C" void kernel_launch(void* const* d_in, const int* in_sizes, int n_in,
                              void* d_out, int out_size, void* d_ws, size_t ws_size,
                              hipStream_t stream){
  const float* x   = (const float*)d_in[0];
  const float* y   = (const float*)d_in[1];
  const float* ew  = (const float*)d_in[2];
  const float* Wp1=(const float*)d_in[3];  const float* bp1=(const float*)d_in[4];
  const float* Wl1=(const float*)d_in[5];  const float* bl1=(const float*)d_in[6];
  const float* Wr1=(const float*)d_in[7];
  const float* Wp2=(const float*)d_in[8];  const float* bp2=(const float*)d_in[9];
  const float* Wl2=(const float*)d_in[10]; const float* bl2=(const float*)d_in[11];
  const float* Wr2=(const float*)d_in[12];
  const float* Wenc=(const float*)d_in[13]; const float* benc=(const float*)d_in[14];
  const float* Wproto=(const float*)d_in[15];
  const float* Wsa=(const float*)d_in[16]; const float* bsa=(const float*)d_in[17];
  const float* Wnc=(const float*)d_in[18]; const float* bnc=(const float*)d_in[19];
  const int* ei=(const int*)d_in[20];
  const int* pb=(const int*)d_in[22];
  const int* pn=(const int*)d_in[23];

  char* p = (char*)d_ws;
  auto carve=[&](size_t b)->void*{ void* r=(void*)p; p += (b+255)&~(size_t)255; return r; };
  u16* XY  = (u16*)carve((size_t)E2*64*2);      // [Y;X] bf16
  u16* S2  = (u16*)carve((size_t)E2*REP*2);     // ANS
  u16* Z   = (u16*)carve((size_t)E2*REP*2);     // [Z1;Z2]
  u16* M   = (u16*)carve((size_t)E2*NPROTO*2);  // [M1;M2] bf16
  float* INVN=(float*)carve((size_t)E2*4);
  float* ANSN=(float*)carve((size_t)EE*4);
  u16* Wp1b = (u16*)carve(64*64*2);
  u16* Wc1b = (u16*)carve(128*128*2);
  u16* Wp2b = (u16*)carve(128*128*2);
  u16* Wc2b = (u16*)carve((size_t)128*256*2);
  u16* Wencb= (u16*)carve(128*128*2);
  u16* Wprotob=(u16*)carve(64*128*2);
  u16* Wncb = (u16*)carve(128*128*2);
  int* topk = (int*)carve((size_t)NN*TOPKK*4);
  float* Pd = (float*)carve((size_t)SINKI*128*SB*4);
  float* D  = (float*)carve(128*4);
  float* P1 = (float*)carve(1024*4);
  float2* P2 = (float2*)carve(1024*8);
  if((size_t)(p - (char*)d_ws) > ws_size) return;

  u16* Z1 = Z;
  u16* Z2 = Z + (size_t)EE*REP;
  u16* M1 = M;
  u16* M2 = M + (size_t)EE*NPROTO;
  float* INVN2 = INVN + EE;

  k_prep<<<2048,256,0,stream>>>(ei, ew, topk,
      Wp1,Wl1,Wr1,Wp2,Wl2,Wr2,Wenc,Wproto,Wnc,
      Wp1b,Wc1b,Wp2b,Wc2b,Wencb,Wprotob,Wncb,
      x, y, XY);

  // single fused encoder: XY -> Z, INVN, M
  k_enc<<<E2/128,256,0,stream>>>(XY, Wp1b, bp1, Wc1b, bl1, Wp2b, bp2,
                                 Wc2b, bl2, Wencb, benc, Wprotob, Z, INVN, M);

  // sinkhorn: 20 stream-ordered iterations on bf16 M + final d
  for(int it=0; it<SINKI; ++it)
    k_sink2<<<512,256,0,stream>>>(M, Pd + (long)(it-1)*128*SB, Pd + (long)it*128*SB, it);
  k_ufinal<<<1,256,0,stream>>>(Pd + (long)(SINKI-1)*128*SB, D);
  k_loss1<<<1024,256,0,stream>>>(M1, M2, D, D+64, P1);

  // fused attention + Wnc (writes ANS into S2)
  k_attnc<<<EE/128,256,0,stream>>>(Z1, topk, Wsa, bsa, Wncb, bnc, S2, ANSN);
  k_loss2<<<1024,256,0,stream>>>(Z2, S2, INVN2, ANSN, pb, pn, P2);

  k_final<<<1,64,0,stream>>>(P1, P2, 1024, 1024, (float*)d_out);
}

// Round 17
// 362.562 us; speedup vs baseline: 1.0358x; 1.0358x over previous
//
#include <hip/hip_runtime.h>
#include <math.h>

#define NN 4096
#define EE 65536
#define E2 (2*EE)
#define DEG 8
#define NPROTO 64
#define REP 128
#define TOPKK 5
#define SINKI 20
#define SB 256          // sink partial slots per (mat,k)

typedef __attribute__((ext_vector_type(8))) short short8;
typedef __attribute__((ext_vector_type(4))) float f32x4;
typedef __attribute__((ext_vector_type(8))) __bf16 bf16x8;
typedef __attribute__((ext_vector_type(4))) unsigned short us4;
typedef unsigned short u16;
typedef unsigned int u32;

__device__ __forceinline__ float b2f(u32 u){
  union { float f; u32 i; } v; v.i = u<<16; return v.f;
}
__device__ __forceinline__ u16 f2b(float f){
  __bf16 h = (__bf16)f;
  return __builtin_bit_cast(u16, h);
}
__device__ __forceinline__ u32 pk2(float lo, float hi){
  return (u32)f2b(lo) | ((u32)f2b(hi)<<16);
}
__device__ __forceinline__ us4 pk4(float a, float b, float c, float d){
  us4 o; o.x=f2b(a); o.y=f2b(b); o.z=f2b(c); o.w=f2b(d); return o;
}
__device__ __forceinline__ f32x4 MFMA_BF16(short8 a, short8 b, f32x4 c){
  return __builtin_amdgcn_mfma_f32_16x16x32_bf16(
      __builtin_bit_cast(bf16x8, a), __builtin_bit_cast(bf16x8, b), c, 0, 0, 0);
}
__device__ __forceinline__ void stage16(const u16* g, u16* l){
  typedef __attribute__((address_space(1))) const unsigned int gu32;
  typedef __attribute__((address_space(3))) unsigned int lu32;
  __builtin_amdgcn_global_load_lds((gu32*)g, (lu32*)l, 16, 0, 0);
}
__device__ __forceinline__ float wsum(float v){
  #pragma unroll
  for(int m=32;m>=1;m>>=1) v += __shfl_xor(v,m);
  return v;
}
__device__ __forceinline__ float r16sum(float v){
  #pragma unroll
  for(int m=8;m>=1;m>>=1) v += __shfl_xor(v,m);
  return v;
}
__device__ __forceinline__ float softplusf(float x){
  if(x > 20.f) return x;
  if(x < -20.f) return __expf(x);
  return log1pf(__expf(x));
}

// ---------------- fused prep: topk + weight packing + input bf16 conversion ----------------
__global__ __launch_bounds__(256) void k_prep(
    const int* __restrict__ ei, const float* __restrict__ ew, int* __restrict__ topk,
    const float* __restrict__ Wp1, const float* __restrict__ Wl1, const float* __restrict__ Wr1,
    const float* __restrict__ Wp2, const float* __restrict__ Wl2, const float* __restrict__ Wr2,
    const float* __restrict__ Wenc, const float* __restrict__ Wproto, const float* __restrict__ Wnc,
    u16* __restrict__ Wp1b, u16* __restrict__ Wc1b, u16* __restrict__ Wp2b, u16* __restrict__ Wc2b,
    u16* __restrict__ Wencb, u16* __restrict__ Wprotob, u16* __restrict__ Wncb,
    const float* __restrict__ x, const float* __restrict__ y, u16* __restrict__ XY){
  const int NW = 4096+16384+16384+32768+16384+8192+16384; // 110592 weight elems
  const int N4 = EE*64/4;
  const int TOTAL = 4096 + NW + 2*N4;
  for(int t0 = blockIdx.x*256+threadIdx.x; t0 < TOTAL; t0 += gridDim.x*256){
    int t = t0;
    if(t < 4096){
      int i = t;
      float val[DEG+1]; int idx[DEG+1]; bool used[DEG+1];
      val[0] = 1.0f; idx[0] = i; used[0]=false;
      for(int k=0;k<DEG;k++){
        int e = i*DEG + k;
        val[k+1] = ew[e];
        idx[k+1] = ei[NN*DEG + e];
        used[k+1] = false;
      }
      for(int s=0;s<TOPKK;s++){
        int best = -1;
        for(int k=0;k<=DEG;k++){
          if(used[k]) continue;
          if(best<0 || val[k]>val[best] || (val[k]==val[best] && idx[k]<idx[best])) best=k;
        }
        used[best]=true;
        topk[i*TOPKK+s]=idx[best];
      }
      continue;
    }
    t -= 4096;
    if(t < NW){
      if(t < 4096){ Wp1b[t]=f2b(Wp1[t]); continue; } t-=4096;
      if(t < 16384){ int c=t>>7, k=t&127;
        Wc1b[t]=f2b(k<64? Wl1[c*64+k] : Wr1[c*64+k-64]); continue; } t-=16384;
      if(t < 16384){ Wp2b[t]=f2b(Wp2[t]); continue; } t-=16384;
      if(t < 32768){ int c=t>>8, k=t&255;
        Wc2b[t]=f2b(k<128? Wl2[c*128+k] : Wr2[c*128+k-128]); continue; } t-=32768;
      if(t < 16384){ Wencb[t]=f2b(Wenc[t]); continue; } t-=16384;
      if(t < 8192){ Wprotob[t]=f2b(Wproto[t]); continue; } t-=8192;
      Wncb[t]=f2b(Wnc[t]); continue;
    }
    t -= NW;
    const float* s = (t<N4)? y : x;
    int k = (t<N4)? t : t-N4;
    float4 v = ((const float4*)s)[k];
    ((us4*)XY)[t] = pk4(v.x, v.y, v.z, v.w);
  }
}

// ---------------- fused layers 1-3: g1(hp1) + wmean64 + dual GEMM + Wp2 ----------------
__global__ __launch_bounds__(256)
void k_f123(const u16* __restrict__ XY,
            const u16* __restrict__ Wp1b, const float* __restrict__ bp1,
            const u16* __restrict__ Wc1b, const float* __restrict__ bl1,
            const u16* __restrict__ Wp2b, const float* __restrict__ bp2,
            u16* __restrict__ H1, u16* __restrict__ HP2){
  __shared__ __align__(16) char arena[53248];
  u16* A  = (u16*)arena;             // 144x64 XY halo (swizzled via source)
  u16* B  = (u16*)(arena + 18432);   // 144x64 hp1 (swizzled)
  u16* C  = (u16*)(arena + 36864);   // 128x64 mean (swizzled)
  u16* T  = (u16*)(arena + 18432);   // 128x128 h1 (aliases B,C — phase 2)
  const int tid = threadIdx.x;
  const int w = tid>>6, l = tid&63;
  const int lr = l&15, kg = l>>4;
  const int rw = w&1, cw = w>>1;
  const int rowoff = rw*64, cbase = cw*64;
  const long rb0 = (long)blockIdx.x*128;
  const long n0 = rb0 & (NN-1), sbase = rb0 - n0;

  for(int c=w;c<18;c+=4){
    int off=c*1024+l*16, row=off>>7;
    int cu=(off&127)^((row&7)<<4);
    long gn=(n0-8+row)&(NN-1);
    stage16(XY+(sbase+gn)*64+(cu>>1), A+c*512);
  }
  __syncthreads();

  for(int t=w; t<9; t+=4){
    f32x4 acc1[4];
    #pragma unroll
    for(int cf=0;cf<4;cf++) acc1[cf]=(f32x4){0.f,0.f,0.f,0.f};
    const char* base = (const char*)A + (t*16+lr)*128;
    const int sw=(lr&7)<<4;
    short8 af0 = *(const short8*)(base + ((kg*16)^sw));
    short8 af1 = *(const short8*)(base + ((64+kg*16)^sw));
    #pragma unroll
    for(int cf=0;cf<4;cf++){
      int ch=cf*16+lr;
      short8 wf0 = *(const short8*)(Wp1b + ch*64 + kg*8);
      short8 wf1 = *(const short8*)(Wp1b + ch*64 + 32 + kg*8);
      acc1[cf]=MFMA_BF16(wf0, af0, acc1[cf]);
      acc1[cf]=MFMA_BF16(wf1, af1, acc1[cf]);
    }
    int row=t*16+lr;
    #pragma unroll
    for(int cf=0;cf<4;cf++){
      int c0=cf*16+kg*4;
      float4 bv=*(const float4*)(bp1+c0);
      us4 o = pk4(fmaxf(acc1[cf][0]+bv.x,0.f), fmaxf(acc1[cf][1]+bv.y,0.f),
                  fmaxf(acc1[cf][2]+bv.z,0.f), fmaxf(acc1[cf][3]+bv.w,0.f));
      *(us4*)((char*)B + row*128 + ((c0*2)^((row&7)<<4))) = o;
    }
  }
  __syncthreads();

  {
    const int s=tid>>5, cp=tid&31;
    float a0=0.f,a1=0.f;
    #pragma unroll
    for(int t2=0;t2<8;t2++){
      int r=s*16+t2;
      u32 v=((const u32*)B)[r*32+(cp^((r&7)<<2))];
      a0+=b2f(v&0xffffu); a1+=b2f(v>>16);
    }
    #pragma unroll
    for(int i=0;i<16;i++){
      int r=s*16+i;
      ((u32*)C)[r*32+(cp^((r&7)<<2))] = pk2(a0*0.125f, a1*0.125f);
      u32 va=((const u32*)B)[(r+8)*32+(cp^((r&7)<<2))];
      u32 vs=((const u32*)B)[r*32+(cp^((r&7)<<2))];
      a0+=b2f(va&0xffffu)-b2f(vs&0xffffu);
      a1+=b2f(va>>16)-b2f(vs>>16);
    }
  }
  __syncthreads();

  f32x4 acc[4][4];
  #pragma unroll
  for(int a=0;a<4;a++)
    #pragma unroll
    for(int b=0;b<4;b++) acc[a][b]=(f32x4){0.f,0.f,0.f,0.f};
  #pragma unroll
  for(int kc=0;kc<2;kc++){
    const char* Ab = kc? ((const char*)A + 8*128) : (const char*)C;
    short8 af[4][2];
    #pragma unroll
    for(int f=0;f<4;f++){
      const char* base = Ab + (rowoff+f*16+lr)*128;
      const int sw = (lr&7)<<4;
      af[f][0] = *(const short8*)(base + ((kg*16)^sw));
      af[f][1] = *(const short8*)(base + ((64+kg*16)^sw));
    }
    #pragma unroll
    for(int cf=0;cf<4;cf++){
      const int ch = cbase + cf*16 + lr;
      short8 wf0 = *(const short8*)(Wc1b + (long)ch*128 + kc*64 + kg*8);
      short8 wf1 = *(const short8*)(Wc1b + (long)ch*128 + kc*64 + 32 + kg*8);
      #pragma unroll
      for(int f=0;f<4;f++){
        acc[cf][f] = MFMA_BF16(wf0, af[f][0], acc[cf][f]);
        acc[cf][f] = MFMA_BF16(wf1, af[f][1], acc[cf][f]);
      }
    }
  }
  __syncthreads();   // B, C, A reads done — T may overwrite

  #pragma unroll
  for(int f=0;f<4;f++){
    const int row = rowoff + f*16 + lr;
    #pragma unroll
    for(int cf=0;cf<4;cf++){
      const int c0 = cbase + cf*16 + kg*4;
      float4 bv = *(const float4*)(bl1 + c0);
      us4 o = pk4(fmaxf(acc[cf][f][0]+bv.x,0.f), fmaxf(acc[cf][f][1]+bv.y,0.f),
                  fmaxf(acc[cf][f][2]+bv.z,0.f), fmaxf(acc[cf][f][3]+bv.w,0.f));
      *(us4*)(H1 + (rb0+row)*128 + c0) = o;
      *(us4*)((char*)T + row*256 + ((c0*2)^((row&7)<<4))) = o;
    }
  }
  __syncthreads();

  #pragma unroll
  for(int a=0;a<4;a++)
    #pragma unroll
    for(int b=0;b<4;b++) acc[a][b]=(f32x4){0.f,0.f,0.f,0.f};
  #pragma unroll
  for(int kc=0;kc<2;kc++){
    short8 af[4][2];
    #pragma unroll
    for(int f=0;f<4;f++){
      const char* base = (const char*)T + (rowoff+f*16+lr)*256;
      const int sw = (lr&7)<<4;
      af[f][0] = *(const short8*)(base + ((kc*128+kg*16)^sw));
      af[f][1] = *(const short8*)(base + ((kc*128+64+kg*16)^sw));
    }
    #pragma unroll
    for(int cf=0;cf<4;cf++){
      const int ch = cbase + cf*16 + lr;
      short8 wf0 = *(const short8*)(Wp2b + (long)ch*128 + kc*64 + kg*8);
      short8 wf1 = *(const short8*)(Wp2b + (long)ch*128 + kc*64 + 32 + kg*8);
      #pragma unroll
      for(int f=0;f<4;f++){
        acc[cf][f] = MFMA_BF16(wf0, af[f][0], acc[cf][f]);
        acc[cf][f] = MFMA_BF16(wf1, af[f][1], acc[cf][f]);
      }
    }
  }
  #pragma unroll
  for(int f=0;f<4;f++){
    const long row = rb0 + rowoff + f*16 + lr;
    #pragma unroll
    for(int cf=0;cf<4;cf++){
      const int c0 = cbase + cf*16 + kg*4;
      float4 bv = *(const float4*)(bp2 + c0);
      us4 o = pk4(fmaxf(acc[cf][f][0]+bv.x,0.f), fmaxf(acc[cf][f][1]+bv.y,0.f),
                  fmaxf(acc[cf][f][2]+bv.z,0.f), fmaxf(acc[cf][f][3]+bv.w,0.f));
      *(us4*)(HP2 + row*128 + c0) = o;
    }
  }
}

// ---------------- fused layer-2 + enc + proto (stage-all-upfront) ----------------
__global__ __launch_bounds__(256)
void k_f456(const u16* __restrict__ HP2, const u16* __restrict__ H1,
            const u16* __restrict__ Wc2b, const float* __restrict__ bl2,
            const u16* __restrict__ Wencb, const float* __restrict__ benc,
            const u16* __restrict__ Wprotob,
            u16* __restrict__ Z, float* __restrict__ INVN, u16* __restrict__ Mout){
  __shared__ __align__(16) char arena[67584];
  u16* h0 = (u16*)arena;
  u16* h1 = (u16*)(arena + 17408);
  u16* a2 = (u16*)(arena + 34816);
  u16* a3 = (u16*)(arena + 51200);
  u16* T  = (u16*)arena;
  __shared__ float lnorm[2][128];
  const int tid = threadIdx.x;
  const int w = tid>>6, l = tid&63;
  const int lr = l&15, kg = l>>4;
  const int rw = w&1, cw = w>>1;
  const int rowoff = rw*64, cbase = cw*64;
  const long rb0 = (long)blockIdx.x*128;
  const long n0 = rb0 & (NN-1), sbase = rb0 - n0;

  for(int c=w;c<17;c+=4){
    int off=c*1024+l*16, row=off>>7, colb=off&127;
    long gn=(n0-8+row)&(NN-1);
    stage16(HP2+(sbase+gn)*128+(colb>>1), h0+c*512);
    stage16(HP2+(sbase+gn)*128+32+(colb>>1), h1+c*512);
  }
  for(int c=w;c<16;c+=4){
    int off=c*1024+l*16, row=off>>7;
    int cu=(off&127)^((row&7)<<4);
    stage16(H1+(rb0+row)*128+(cu>>1), a2+c*512);
    stage16(H1+(rb0+row)*128+64+(cu>>1), a3+c*512);
  }
  __syncthreads();

  u32 o0v[16], o1v[16];
  {
    const int s = tid>>5, cp = tid&31;
    const u32* r0 = (const u32*)h0;
    const u32* r1 = (const u32*)h1;
    float a00=0.f,a01=0.f,a10=0.f,a11=0.f;
    #pragma unroll
    for(int t=0;t<8;t++){
      u32 v0=r0[(s*16+t)*32+cp]; a00+=b2f(v0&0xffffu); a01+=b2f(v0>>16);
      u32 v1=r1[(s*16+t)*32+cp]; a10+=b2f(v1&0xffffu); a11+=b2f(v1>>16);
    }
    #pragma unroll
    for(int i=0;i<16;i++){
      int r=s*16+i;
      o0v[i]=pk2(a00*0.125f, a01*0.125f);
      o1v[i]=pk2(a10*0.125f, a11*0.125f);
      u32 va0=r0[(r+8)*32+cp], vs0=r0[r*32+cp];
      a00+=b2f(va0&0xffffu)-b2f(vs0&0xffffu);
      a01+=b2f(va0>>16)-b2f(vs0>>16);
      u32 va1=r1[(r+8)*32+cp], vs1=r1[r*32+cp];
      a10+=b2f(va1&0xffffu)-b2f(vs1&0xffffu);
      a11+=b2f(va1>>16)-b2f(vs1>>16);
    }
    __syncthreads();
    u32* w0=(u32*)h0; u32* w1=(u32*)h1;
    #pragma unroll
    for(int i=0;i<16;i++){
      int r=s*16+i;
      int idx=r*32+(cp^((r&7)<<2));
      w0[idx]=o0v[i];
      w1[idx]=o1v[i];
    }
  }
  __syncthreads();

  f32x4 acc[4][4];
  #pragma unroll
  for(int a=0;a<4;a++)
    #pragma unroll
    for(int b=0;b<4;b++) acc[a][b]=(f32x4){0.f,0.f,0.f,0.f};
  #pragma unroll
  for(int kc=0;kc<4;kc++){
    const char* Ab = (kc==0)? (const char*)h0 : (kc==1)? (const char*)h1
                   : (kc==2)? (const char*)a2 : (const char*)a3;
    short8 af[4][2];
    #pragma unroll
    for(int f=0;f<4;f++){
      const char* base = Ab + (rowoff+f*16+lr)*128;
      const int sw = (lr&7)<<4;
      af[f][0] = *(const short8*)(base + ((kg*16)^sw));
      af[f][1] = *(const short8*)(base + ((64+kg*16)^sw));
    }
    #pragma unroll
    for(int cf=0;cf<4;cf++){
      const int ch = cbase + cf*16 + lr;
      short8 wf0 = *(const short8*)(Wc2b + (long)ch*256 + kc*64 + kg*8);
      short8 wf1 = *(const short8*)(Wc2b + (long)ch*256 + kc*64 + 32 + kg*8);
      #pragma unroll
      for(int f=0;f<4;f++){
        acc[cf][f] = MFMA_BF16(wf0, af[f][0], acc[cf][f]);
        acc[cf][f] = MFMA_BF16(wf1, af[f][1], acc[cf][f]);
      }
    }
  }
  __syncthreads();   // all chunk reads done — T may alias h0/h1

  #pragma unroll
  for(int f=0;f<4;f++){
    const int row = rowoff + f*16 + lr;
    #pragma unroll
    for(int cf=0;cf<4;cf++){
      const int c0 = cbase + cf*16 + kg*4;
      float4 bv = *(const float4*)(bl2 + c0);
      us4 o = pk4(fmaxf(acc[cf][f][0]+bv.x,0.f), fmaxf(acc[cf][f][1]+bv.y,0.f),
                  fmaxf(acc[cf][f][2]+bv.z,0.f), fmaxf(acc[cf][f][3]+bv.w,0.f));
      *(us4*)((char*)T + row*256 + ((c0*2)^((row&7)<<4))) = o;
    }
  }
  __syncthreads();

  #pragma unroll
  for(int a=0;a<4;a++)
    #pragma unroll
    for(int b=0;b<4;b++) acc[a][b]=(f32x4){0.f,0.f,0.f,0.f};
  #pragma unroll
  for(int kc=0;kc<2;kc++){
    short8 af[4][2];
    #pragma unroll
    for(int f=0;f<4;f++){
      const char* base = (const char*)T + (rowoff+f*16+lr)*256;
      const int sw = (lr&7)<<4;
      af[f][0] = *(const short8*)(base + ((kc*128+kg*16)^sw));
      af[f][1] = *(const short8*)(base + ((kc*128+64+kg*16)^sw));
    }
    #pragma unroll
    for(int cf=0;cf<4;cf++){
      const int ch = cbase + cf*16 + lr;
      short8 wf0 = *(const short8*)(Wencb + (long)ch*128 + kc*64 + kg*8);
      short8 wf1 = *(const short8*)(Wencb + (long)ch*128 + kc*64 + 32 + kg*8);
      #pragma unroll
      for(int f=0;f<4;f++){
        acc[cf][f] = MFMA_BF16(wf0, af[f][0], acc[cf][f]);
        acc[cf][f] = MFMA_BF16(wf1, af[f][1], acc[cf][f]);
      }
    }
  }
  __syncthreads();   // all T(h2) reads done

  {
    float sn[4] = {0.f,0.f,0.f,0.f};
    #pragma unroll
    for(int f=0;f<4;f++){
      #pragma unroll
      for(int cf=0;cf<4;cf++){
        const int c0 = cbase + cf*16 + kg*4;
        float4 bv = *(const float4*)(benc + c0);
        float v0=acc[cf][f][0]+bv.x, v1=acc[cf][f][1]+bv.y;
        float v2=acc[cf][f][2]+bv.z, v3=acc[cf][f][3]+bv.w;
        sn[f] += v0*v0+v1*v1+v2*v2+v3*v3;
      }
      float s = sn[f];
      s += __shfl_xor(s, 16);
      s += __shfl_xor(s, 32);
      if(kg==0) lnorm[cw][rw*64 + f*16 + lr] = s;
    }
  }
  __syncthreads();
  if(tid < 128){
    float s = lnorm[0][tid] + lnorm[1][tid];
    INVN[rb0 + tid] = 1.0f/fmaxf(sqrtf(s), 1e-12f);
  }
  #pragma unroll
  for(int f=0;f<4;f++){
    const int row = rowoff + f*16 + lr;
    float sr = lnorm[0][row] + lnorm[1][row];
    float inv = 1.0f/fmaxf(sqrtf(sr), 1e-12f);
    #pragma unroll
    for(int cf=0;cf<4;cf++){
      const int c0 = cbase + cf*16 + kg*4;
      float4 bv = *(const float4*)(benc + c0);
      float v0=acc[cf][f][0]+bv.x, v1=acc[cf][f][1]+bv.y;
      float v2=acc[cf][f][2]+bv.z, v3=acc[cf][f][3]+bv.w;
      *(us4*)(Z + (rb0+row)*128 + c0) = pk4(v0,v1,v2,v3);
      *(us4*)((char*)T + row*256 + ((c0*2)^((row&7)<<4))) = pk4(v0*inv,v1*inv,v2*inv,v3*inv);
    }
  }
  __syncthreads();

  f32x4 acc3[2][4];
  #pragma unroll
  for(int a=0;a<2;a++)
    #pragma unroll
    for(int b=0;b<4;b++) acc3[a][b]=(f32x4){0.f,0.f,0.f,0.f};
  #pragma unroll
  for(int kc=0;kc<2;kc++){
    short8 af[4][2];
    #pragma unroll
    for(int f=0;f<4;f++){
      const char* base = (const char*)T + (rowoff+f*16+lr)*256;
      const int sw = (lr&7)<<4;
      af[f][0] = *(const short8*)(base + ((kc*128+kg*16)^sw));
      af[f][1] = *(const short8*)(base + ((kc*128+64+kg*16)^sw));
    }
    #pragma unroll
    for(int cf=0;cf<2;cf++){
      const int ch = cw*32 + cf*16 + lr;
      short8 wf0 = *(const short8*)(Wprotob + (long)ch*128 + kc*64 + kg*8);
      short8 wf1 = *(const short8*)(Wprotob + (long)ch*128 + kc*64 + 32 + kg*8);
      #pragma unroll
      for(int f=0;f<4;f++){
        acc3[cf][f] = MFMA_BF16(wf0, af[f][0], acc3[cf][f]);
        acc3[cf][f] = MFMA_BF16(wf1, af[f][1], acc3[cf][f]);
      }
    }
  }
  #pragma unroll
  for(int f=0;f<4;f++){
    const long row = rb0 + rowoff + f*16 + lr;
    #pragma unroll
    for(int cf=0;cf<2;cf++){
      const int c0 = cw*32 + cf*16 + kg*4;
      *(us4*)(Mout + row*64 + c0) = pk4(__expf(20.f*acc3[cf][f][0]), __expf(20.f*acc3[cf][f][1]),
                                        __expf(20.f*acc3[cf][f][2]), __expf(20.f*acc3[cf][f][3]));
    }
  }
}

// ---------------- sinkhorn iteration (bf16 M) ----------------
__global__ __launch_bounds__(256)
void k_sink2(const u16* __restrict__ M, const float* __restrict__ Pdprev,
             float* __restrict__ Pdcur, int it){
  __shared__ float T[4][64*33];
  __shared__ float ulds[NPROTO];
  __shared__ float redw[4][NPROTO];
  const int tid = threadIdx.x, b = blockIdx.x;
  const int wv = tid>>6, l = tid&63;
  const int mat = b>>8, bi = b&255;
  const long row = (long)mat*EE + (long)bi*256 + wv*64 + l;

  float m[64];
  #pragma unroll
  for(int j=0;j<8;j++){
    short8 v = *(const short8*)(M + row*64 + j*8);
    #pragma unroll
    for(int e=0;e<8;e++) m[j*8+e] = b2f((u16)v[e]);
  }

  if(it > 0 && tid < 128){
    int k = tid>>1, half = tid&1;
    const float4* src = (const float4*)(Pdprev + (long)(mat*64+k)*SB + half*128);
    float s = 0.f;
    #pragma unroll
    for(int j=0;j<32;j++){ float4 q = src[j]; s += q.x+q.y+q.z+q.w; }
    s += __shfl_xor(s, 1);
    if(half==0) ulds[k] = 1.0f/((float)NPROTO * s);
  }
  __syncthreads();

  float vv = 1.f;
  if(it > 0){
    float s = 0.f;
    #pragma unroll
    for(int k=0;k<64;k++) s += m[k]*ulds[k];
    vv = 1.0f/((float)EE * s);
  }

  float* Tw = &T[wv][0];
  const int col = l&31, rh = l>>5;
  #pragma unroll
  for(int h=0;h<2;h++){
    #pragma unroll
    for(int kk=0;kk<32;kk++) Tw[l*33+kk] = m[h*32+kk]*vv;
    __syncthreads();
    float s = 0.f;
    #pragma unroll
    for(int j=0;j<32;j++) s += Tw[(rh*32+j)*33 + col];
    s += __shfl_xor(s, 32);
    if(l<32) redw[wv][h*32+l] = s;
    __syncthreads();
  }
  if(tid < 64){
    float s = redw[0][tid]+redw[1][tid]+redw[2][tid]+redw[3][tid];
    Pdcur[(long)(mat*64+tid)*SB + bi] = s;
  }
}

// ---------------- prototype loss from M (D folded in; 16 lanes/row, 4 rows/wave) ----------------
__global__ __launch_bounds__(256) void k_loss1(const u16* __restrict__ M1, const u16* __restrict__ M2,
                                               const float* __restrict__ Pdlast,
                                               float* __restrict__ p1){
  __shared__ __align__(16) float Dsh[128];
  const int tid = threadIdx.x, wv = tid>>6;
  const int gw = blockIdx.x*4 + wv;
  const int l = tid&63, g = l>>4, li = l&15;
  const int nw = gridDim.x*4;
  {
    int mk = tid>>1, half = tid&1;
    const float4* src = (const float4*)(Pdlast + (long)mk*SB + half*128);
    float s = 0.f;
    #pragma unroll
    for(int j=0;j<32;j++){ float4 q = src[j]; s += q.x+q.y+q.z+q.w; }
    s += __shfl_xor(s, 1);
    if(half==0) Dsh[mk] = s;
  }
  __syncthreads();
  float4 dv1 = ((const float4*)Dsh)[li];
  float4 dv2 = ((const float4*)(Dsh+64))[li];
  const float inp = 1.0f/(float)NPROTO;
  float u1v[4] = { inp/dv1.x, inp/dv1.y, inp/dv1.z, inp/dv1.w };
  float u2v[4] = { inp/dv2.x, inp/dv2.y, inp/dv2.z, inp/dv2.w };
  const float i6 = 1.0f/6.0f;
  float lsum = 0.f;
  for(long r0 = (long)gw*4; r0 < EE; r0 += (long)nw*4){
    long r = r0 + g;
    uint2 w1 = ((const uint2*)(M1 + r*NPROTO))[li];
    uint2 w2 = ((const uint2*)(M2 + r*NPROTO))[li];
    float m1v[4] = { b2f(w1.x&0xffffu), b2f(w1.x>>16), b2f(w1.y&0xffffu), b2f(w1.y>>16) };
    float m2v[4] = { b2f(w2.x&0xffffu), b2f(w2.x>>16), b2f(w2.y&0xffffu), b2f(w2.y>>16) };
    float x1v[4], x2v[4], a1v[4], a2v[4];
    #pragma unroll
    for(int j=0;j<4;j++){
      x1v[j] = __logf(m1v[j])*i6;
      x2v[j] = __logf(m2v[j])*i6;
      a1v[j] = m1v[j]*u1v[j];
      a2v[j] = m2v[j]*u2v[j];
    }
    float S1 = r16sum(a1v[0]+a1v[1]+a1v[2]+a1v[3]);
    float S2 = r16sum(a2v[0]+a2v[1]+a2v[2]+a2v[3]);
    float mx1 = fmaxf(fmaxf(x1v[0],x1v[1]),fmaxf(x1v[2],x1v[3]));
    float mx2 = fmaxf(fmaxf(x2v[0],x2v[1]),fmaxf(x2v[2],x2v[3]));
    #pragma unroll
    for(int m=8;m>=1;m>>=1){ mx1=fmaxf(mx1,__shfl_xor(mx1,m)); mx2=fmaxf(mx2,__shfl_xor(mx2,m)); }
    float Z1 = r16sum(__expf(x1v[0]-mx1)+__expf(x1v[1]-mx1)+__expf(x1v[2]-mx1)+__expf(x1v[3]-mx1));
    float Z2 = r16sum(__expf(x2v[0]-mx2)+__expf(x2v[1]-mx2)+__expf(x2v[2]-mx2)+__expf(x2v[3]-mx2));
    float o1 = mx1 + __logf(Z1);
    float o2 = mx2 + __logf(Z2);
    float t1 = r16sum(a1v[0]*(x2v[0]-o2)+a1v[1]*(x2v[1]-o2)+a1v[2]*(x2v[2]-o2)+a1v[3]*(x2v[3]-o2)) / S1;
    float t2 = r16sum(a2v[0]*(x1v[0]-o1)+a2v[1]*(x1v[1]-o1)+a2v[2]*(x1v[2]-o1)+a2v[3]*(x1v[3]-o1)) / S2;
    if(li==0) lsum += t1+t2;
  }
  lsum = wsum(lsum);
  __shared__ float red[4];
  if(l==0) red[wv]=lsum;
  __syncthreads();
  if(tid==0) p1[blockIdx.x] = red[0]+red[1]+red[2]+red[3];
}

// ---------------- fused attention + Wnc GEMM ----------------
__global__ __launch_bounds__(256)
void k_attnc(const u16* __restrict__ Z1, const int* __restrict__ topk,
             const float* __restrict__ Wsa, const float* __restrict__ bsa,
             const u16* __restrict__ Wncb, const float* __restrict__ bnc,
             u16* __restrict__ ANS, float* __restrict__ ansn){
  __shared__ __align__(16) u16 T[128*128];
  __shared__ float lnorm[2][128];
  const int tid = threadIdx.x;
  const int w = tid>>6, l = tid&63;
  const int lr = l&15, kg = l>>4;
  const int g = l>>4, li = l&15;
  const long rb0 = (long)blockIdx.x*128;

  float2 wsa[4];
  #pragma unroll
  for(int j=0;j<4;j++) wsa[j] = ((const float2*)Wsa)[li*4+j];
  const float bs = bsa[0];
  for(int it=0; it<8; ++it){
    int row = it*16 + w*4 + g;     // 0..127
    long r = rb0 + row;
    int b = (int)(r >> 12);
    int n = (int)(r & (NN-1));
    u32 nb[TOPKK][4];
    float lg[TOPKK];
    #pragma unroll
    for(int k=0;k<TOPKK;k++){
      int idx = topk[n*TOPKK+k];
      uint4 v = ((const uint4*)(Z1 + ((long)(b<<12)+idx)*REP))[li];
      nb[k][0]=v.x; nb[k][1]=v.y; nb[k][2]=v.z; nb[k][3]=v.w;
      float s = 0.f;
      #pragma unroll
      for(int j=0;j<4;j++)
        s += b2f(nb[k][j]&0xffffu)*wsa[j].x + b2f(nb[k][j]>>16)*wsa[j].y;
      lg[k] = r16sum(s) + bs;
    }
    float mx = lg[0];
    #pragma unroll
    for(int k=1;k<TOPKK;k++) mx = fmaxf(mx,lg[k]);
    float Zs=0.f;
    #pragma unroll
    for(int k=0;k<TOPKK;k++){ lg[k]=__expf(lg[k]-mx); Zs+=lg[k]; }
    float iZ = 1.0f/Zs;
    uint4 o;
    u32 ov[4];
    #pragma unroll
    for(int j=0;j<4;j++){
      float o0=0.f, o1=0.f;
      #pragma unroll
      for(int k=0;k<TOPKK;k++){
        float a = lg[k]*iZ;
        o0 += a*b2f(nb[k][j]&0xffffu);
        o1 += a*b2f(nb[k][j]>>16);
      }
      ov[j] = pk2(o0, o1);
    }
    o.x=ov[0]; o.y=ov[1]; o.z=ov[2]; o.w=ov[3];
    *(uint4*)((char*)T + (long)row*256 + ((li*16)^((row&7)<<4))) = o;
  }
  __syncthreads();

  const int rw = w&1, cw = w>>1;
  const int rowoff = rw*64, cbase = cw*64;
  f32x4 acc[4][4];
  #pragma unroll
  for(int a=0;a<4;a++)
    #pragma unroll
    for(int b=0;b<4;b++) acc[a][b]=(f32x4){0.f,0.f,0.f,0.f};
  #pragma unroll
  for(int kc=0;kc<2;kc++){
    short8 af[4][2];
    #pragma unroll
    for(int f=0;f<4;f++){
      const char* base = (const char*)T + (rowoff+f*16+lr)*256;
      const int sw = (lr&7)<<4;
      af[f][0] = *(const short8*)(base + ((kc*128+kg*16)^sw));
      af[f][1] = *(const short8*)(base + ((kc*128+64+kg*16)^sw));
    }
    #pragma unroll
    for(int cf=0;cf<4;cf++){
      const int ch = cbase + cf*16 + lr;
      short8 wf0 = *(const short8*)(Wncb + (long)ch*128 + kc*64 + kg*8);
      short8 wf1 = *(const short8*)(Wncb + (long)ch*128 + kc*64 + 32 + kg*8);
      #pragma unroll
      for(int f=0;f<4;f++){
        acc[cf][f] = MFMA_BF16(wf0, af[f][0], acc[cf][f]);
        acc[cf][f] = MFMA_BF16(wf1, af[f][1], acc[cf][f]);
      }
    }
  }
  float sn[4] = {0.f,0.f,0.f,0.f};
  #pragma unroll
  for(int f=0;f<4;f++){
    const long row = rb0 + rowoff + f*16 + lr;
    #pragma unroll
    for(int cf=0;cf<4;cf++){
      const int c0 = cbase + cf*16 + kg*4;
      float4 bv = *(const float4*)(bnc + c0);
      float v0=acc[cf][f][0]+bv.x, v1=acc[cf][f][1]+bv.y;
      float v2=acc[cf][f][2]+bv.z, v3=acc[cf][f][3]+bv.w;
      sn[f] += v0*v0+v1*v1+v2*v2+v3*v3;
      *(us4*)(ANS + row*128 + c0) = pk4(v0,v1,v2,v3);
    }
  }
  #pragma unroll
  for(int f=0;f<4;f++){
    float s = sn[f];
    s += __shfl_xor(s, 16);
    s += __shfl_xor(s, 32);
    if(kg==0) lnorm[cw][rowoff + f*16 + lr] = s;
  }
  __syncthreads();
  if(tid < 128){
    float s = lnorm[0][tid] + lnorm[1][tid];
    ansn[rb0 + tid] = 1.0f/fmaxf(sqrtf(s), 1e-12f);
  }
}

// ---------------- discriminator loss + acc (16 lanes/row, 4 rows/wave) ----------------
__global__ __launch_bounds__(256) void k_loss2(const u16* __restrict__ Z2, const u16* __restrict__ ANS,
                                               const float* __restrict__ invn2, const float* __restrict__ ansn,
                                               const int* __restrict__ pb, const int* __restrict__ pn,
                                               float2* __restrict__ p2){
  const int tid = threadIdx.x, wv = tid>>6;
  const int gw = blockIdx.x*4 + wv;
  const int l = tid&63, g = l>>4, li = l&15;
  const int nw = gridDim.x*4;
  float lsum=0.f, asum=0.f;
  for(long r0 = (long)gw*4; r0 < EE; r0 += (long)nw*4){
    long r = r0 + g;
    int b = (int)(r>>12), n = (int)(r&(NN-1));
    long rfrow = (long)pb[b]*NN + pn[n];
    uint4 zv = ((const uint4*)(Z2 + r*REP))[li];
    uint4 av = ((const uint4*)(ANS + r*REP))[li];
    uint4 fv = ((const uint4*)(ANS + rfrow*REP))[li];
    float sr=0.f, sf=0.f;
    {
      u32 za[4]={zv.x,zv.y,zv.z,zv.w}, aa[4]={av.x,av.y,av.z,av.w}, fa[4]={fv.x,fv.y,fv.z,fv.w};
      #pragma unroll
      for(int j=0;j<4;j++){
        float z0=b2f(za[j]&0xffffu), z1=b2f(za[j]>>16);
        sr += z0*b2f(aa[j]&0xffffu) + z1*b2f(aa[j]>>16);
        sf += z0*b2f(fa[j]&0xffffu) + z1*b2f(fa[j]>>16);
      }
    }
    sr = r16sum(sr); sf = r16sum(sf);
    if(li==0){
      float in2 = invn2[r];
      float scrl = sr*in2*ansn[r];
      float scfk = sf*in2*ansn[rfrow];
      lsum += softplusf(-scrl) + softplusf(scfk);
      asum += (scrl>0.f?1.f:0.f) + (scfk>0.f?0.f:1.f);
    }
  }
  lsum = wsum(lsum); asum = wsum(asum);
  __shared__ float rl[4], ra[4];
  if(l==0){ rl[wv]=lsum; ra[wv]=asum; }
  __syncthreads();
  if(tid==0){
    float2 o; o.x=rl[0]+rl[1]+rl[2]+rl[3]; o.y=ra[0]+ra[1]+ra[2]+ra[3];
    p2[blockIdx.x]=o;
  }
}

__global__ void k_final(const float* __restrict__ p1, const float2* __restrict__ p2,
                        int n1, int n2, float* __restrict__ out){
  int l = threadIdx.x;        // 64 threads
  double s1=0,s2=0,sa=0;
  for(int i=l;i<n1;i+=64) s1 += (double)p1[i];
  for(int i=l;i<n2;i+=64){ float2 v=p2[i]; s2+=(double)v.x; sa+=(double)v.y; }
  #pragma unroll
  for(int m=32;m>=1;m>>=1){ s1+=__shfl_xor(s1,m); s2+=__shfl_xor(s2,m); sa+=__shfl_xor(sa,m); }
  if(l==0){
    double loss1 = -s1/(double)EE;
    double loss2 = s2/(double)(2*EE);
    double acc   = sa/(double)(2*EE);
    out[0]=(float)(loss1+loss2);
    out[1]=(float)acc;
  }
}

// ---------------- host ----------------
extern "C" void kernel_launch(void* const* d_in, const int* in_sizes, int n_in,
                              void* d_out, int out_size, void* d_ws, size_t ws_size,
                              hipStream_t stream){
  const float* x   = (const float*)d_in[0];
  const float* y   = (const float*)d_in[1];
  const float* ew  = (const float*)d_in[2];
  const float* Wp1=(const float*)d_in[3];  const float* bp1=(const float*)d_in[4];
  const float* Wl1=(const float*)d_in[5];  const float* bl1=(const float*)d_in[6];
  const float* Wr1=(const float*)d_in[7];
  const float* Wp2=(const float*)d_in[8];  const float* bp2=(const float*)d_in[9];
  const float* Wl2=(const float*)d_in[10]; const float* bl2=(const float*)d_in[11];
  const float* Wr2=(const float*)d_in[12];
  const float* Wenc=(const float*)d_in[13]; const float* benc=(const float*)d_in[14];
  const float* Wproto=(const float*)d_in[15];
  const float* Wsa=(const float*)d_in[16]; const float* bsa=(const float*)d_in[17];
  const float* Wnc=(const float*)d_in[18]; const float* bnc=(const float*)d_in[19];
  const int* ei=(const int*)d_in[20];
  const int* pb=(const int*)d_in[22];
  const int* pn=(const int*)d_in[23];

  char* p = (char*)d_ws;
  auto carve=[&](size_t b)->void*{ void* r=(void*)p; p += (b+255)&~(size_t)255; return r; };
  u16* XY  = (u16*)carve((size_t)E2*64*2);      // [Y;X] bf16
  u16* S2  = (u16*)carve((size_t)E2*REP*2);     // H1, later ANS
  u16* S1b = (u16*)carve((size_t)E2*REP*2);     // HP2
  u16* Z   = (u16*)carve((size_t)E2*REP*2);     // [Z1;Z2]
  u16* M   = (u16*)carve((size_t)E2*NPROTO*2);  // [M1;M2] bf16
  float* INVN=(float*)carve((size_t)E2*4);
  float* ANSN=(float*)carve((size_t)EE*4);
  u16* Wp1b = (u16*)carve(64*64*2);
  u16* Wc1b = (u16*)carve(128*128*2);
  u16* Wp2b = (u16*)carve(128*128*2);
  u16* Wc2b = (u16*)carve((size_t)128*256*2);
  u16* Wencb= (u16*)carve(128*128*2);
  u16* Wprotob=(u16*)carve(64*128*2);
  u16* Wncb = (u16*)carve(128*128*2);
  int* topk = (int*)carve((size_t)NN*TOPKK*4);
  float* Pd = (float*)carve((size_t)SINKI*128*SB*4);
  float* P1 = (float*)carve(1024*4);
  float2* P2 = (float2*)carve(1024*8);
  if((size_t)(p - (char*)d_ws) > ws_size) return;

  u16* Z1 = Z;
  u16* Z2 = Z + (size_t)EE*REP;
  u16* M1 = M;
  u16* M2 = M + (size_t)EE*NPROTO;
  float* INVN2 = INVN + EE;

  k_prep<<<2048,256,0,stream>>>(ei, ew, topk,
      Wp1,Wl1,Wr1,Wp2,Wl2,Wr2,Wenc,Wproto,Wnc,
      Wp1b,Wc1b,Wp2b,Wc2b,Wencb,Wprotob,Wncb,
      x, y, XY);

  // fused encoder: {g1, wmean64, dual-1, Wp2} then {wmean128, dual-2, Wenc, Wproto}
  k_f123<<<E2/128,256,0,stream>>>(XY, Wp1b, bp1, Wc1b, bl1, Wp2b, bp2, S2, S1b);
  k_f456<<<E2/128,256,0,stream>>>(S1b, S2, Wc2b, bl2, Wencb, benc, Wprotob, Z, INVN, M);

  // sinkhorn: 20 stream-ordered iterations on bf16 M
  for(int it=0; it<SINKI; ++it)
    k_sink2<<<512,256,0,stream>>>(M, Pd + (long)(it-1)*128*SB, Pd + (long)it*128*SB, it);
  k_loss1<<<1024,256,0,stream>>>(M1, M2, Pd + (long)(SINKI-1)*128*SB, P1);

  // fused attention + Wnc (writes ANS into S2, H1 dead)
  k_attnc<<<EE/128,256,0,stream>>>(Z1, topk, Wsa, bsa, Wncb, bnc, S2, ANSN);
  k_loss2<<<1024,256,0,stream>>>(Z2, S2, INVN2, ANSN, pb, pn, P2);

  k_final<<<1,64,0,stream>>>(P1, P2, 1024, 1024, (float*)d_out);
}